// Round 5
// baseline (146.853 us; speedup 1.0000x reference)
//
#include <hip/hip_runtime.h>

// out[c, y, w] = x[p, c, oy, ox];  p = iy*9+jx, iy=y/126, jx=w/126,
// oy=y-126*iy, ox=w-126*jx.  x:(81,64,128,128) f32; out:(64,1024,1024) f32.
//
// Round 5: LDS-decoupled copy. Rounds 1-4 (width, density, ordering, slabs)
// all ~118 us. This version makes BOTH HBM streams look exactly like the
// 6.3 TB/s copy ubench: reads = aligned float4 of full 128-float input rows
// (wave = 2 dense 512-B runs), writes = aligned float4 of output rows
// (wave = 1 dense 1024-B run). The 126<->128 shift is resolved in LDS:
// staged rows are gathered back with ds_read_b64 (output PAIRS never split a
// jx-segment and are 8-B aligned). LDS demand ~2 TB/s << 69 TB/s ceiling,
// so stride conflicts there are irrelevant.
//
// Tiling: row index R = c*1024 + y (65536 rows). Block owns 32 consecutive
// rows = 4 groups of 8. Per group: stage 8 rows x (8 full segs * 128 + 16
// tail floats) = 8 x 1040 floats (33 KB LDS, 4 blocks/CU), then emit
// 8 x 1024 floats. Input quads linearize so LDS offset = 4*q exactly.

__global__ __launch_bounds__(256) void patch_gather_lds(
    const float* __restrict__ x, float* __restrict__ out) {
    __shared__ float lds[8][1040];
    const unsigned t = threadIdx.x;
    const unsigned Rblock = blockIdx.x * 32u;

    for (unsigned g = 0; g < 4u; ++g) {
        const unsigned R0 = Rblock + g * 8u;

        // ---- stage: 2080 input quads -> LDS[4*q] ----
        // q = 260*r + u; u<256: jx=u>>5 (0..7), quad u&31 of the 128-float row;
        // u in 256..259: jx=8, first 16 floats. LDS float-offset = 4*q.
        #pragma unroll
        for (unsigned p = 0; p < 9u; ++p) {
            const unsigned q = t + p * 256u;
            if (q < 2080u) {
                const unsigned r  = q / 260u;          // magic-mul
                const unsigned u  = q - r * 260u;      // 0..259
                const unsigned R  = R0 + r;
                const unsigned c  = R >> 10;
                const unsigned y  = R & 1023u;
                const unsigned iy = y / 126u;          // magic-mul
                const unsigned oy = y - iy * 126u;
                const unsigned jx = u >> 5;
                const size_t addr = ((size_t)((iy * 9u + jx) * 64u + c) << 14)
                                  + (oy << 7) + ((u & 31u) << 2);
                *reinterpret_cast<float4*>(&lds[0][0] + 4u * q) =
                    *reinterpret_cast<const float4*>(&x[addr]);
            }
        }
        __syncthreads();

        // ---- emit: 8 rows x 256 aligned float4 stores ----
        // thread t owns out quad w0 = 4t of every row; the two pairs of the
        // quad never split a jx-segment (segment starts 126*jx are even).
        const unsigned w0  = t << 2;
        const unsigned jxA = w0 / 126u;                // magic-mul (hoisted, p-invariant)
        const unsigned oxA = w0 - jxA * 126u;
        const unsigned w2  = w0 + 2u;
        const unsigned jxB = w2 / 126u;
        const unsigned oxB = w2 - jxB * 126u;
        const unsigned offA = (jxA << 7) + oxA;        // float offset in row
        const unsigned offB = (jxB << 7) + oxB;
        #pragma unroll
        for (unsigned p = 0; p < 8u; ++p) {
            const float2 a = *reinterpret_cast<const float2*>(&lds[p][offA]);
            const float2 b = *reinterpret_cast<const float2*>(&lds[p][offB]);
            float4 v; v.x = a.x; v.y = a.y; v.z = b.x; v.w = b.y;
            const unsigned R = R0 + p;
            *reinterpret_cast<float4*>(&out[((size_t)R << 10) + w0]) = v;
        }
        __syncthreads();
    }
}

extern "C" void kernel_launch(void* const* d_in, const int* in_sizes, int n_in,
                              void* d_out, int out_size, void* d_ws, size_t ws_size,
                              hipStream_t stream) {
    const float* x = (const float*)d_in[0];
    float* out = (float*)d_out;
    // 65536 rows / 32 rows-per-block = 2048 blocks (exact).
    patch_gather_lds<<<2048, 256, 0, stream>>>(x, out);
}

// Round 6
// 103.271 us; speedup vs baseline: 1.4220x; 1.4220x over previous
//
#include <hip/hip_runtime.h>

// out[c, y, w] = x[p, c, oy, ox]
//   iy = y / 126, jx = w / 126  (clamps never trigger for y,w < 1024)
//   oy = y - iy*126, ox = w - jx*126, p = iy*9 + jx
// x: (81, 64, 128, 128) f32; out: (64, 1024, 1024) f32. Pure injective gather,
// memory-bound, ZERO reuse of any byte.
//
// Round 6: round-3 structure (fastest so far, 116.0 us) + NON-TEMPORAL hints
// on both streams. Rounds 1-5 falsified load width, per-instruction lane
// density, work ordering, and LDS re-shaping as limiters (all ~118 us).
// Remaining un-tried variable: L2 policy. 529 MB streams through 32 MB L2
// with allocate+writeback -> every fetch forces an eviction, dirty-writeback
// pipeline competes with demand fetches. nt load = no retention (read stream
// stops forcing evictions); nt store = streaming write, no pollution.
//
// Thread granule: one output PAIR (never splits a jx-segment since boundaries
// 126k are even; 8-B aligned both sides; lane-dense 512 B per instruction).

typedef float v2f __attribute__((ext_vector_type(2)));

__global__ __launch_bounds__(256) void patch_gather_kernel(
    const float* __restrict__ x, float* __restrict__ out, unsigned n_pairs) {
    const unsigned tid = threadIdx.x;
    const unsigned chunk = blockDim.x * 4u;                 // pairs per block-iter
    const unsigned stride = gridDim.x * chunk;
    for (unsigned base = blockIdx.x * chunk + tid; base < n_pairs; base += stride) {
        #pragma unroll
        for (int k = 0; k < 4; ++k) {
            const unsigned q = base + (unsigned)k * 256u;   // pair index, lanes contiguous
            if (q >= n_pairs) break;                        // exact fit in practice
            const unsigned idx = q << 1;                    // flat output index (even)
            const unsigned c  = idx >> 20;                  // H*W = 2^20
            const unsigned y  = (idx >> 10) & 1023u;
            const unsigned w0 = idx & 1023u;                // even

            const unsigned iy = y / 126u;                   // magic-mul
            const unsigned oy = y - iy * 126u;
            const unsigned jx = w0 / 126u;                  // magic-mul
            const unsigned ox = w0 - jx * 126u;             // even

            // addr = ((p*64 + c) << 14) + (oy << 7) + ox,  p = iy*9 + jx
            const size_t addr = ((size_t)(iy * 576u + c) << 14)
                              + ((size_t)jx << 20) + (oy << 7) + ox;

            const v2f v = __builtin_nontemporal_load(
                reinterpret_cast<const v2f*>(&x[addr]));
            __builtin_nontemporal_store(
                v, reinterpret_cast<v2f*>(&out[idx]));
        }
    }
}

extern "C" void kernel_launch(void* const* d_in, const int* in_sizes, int n_in,
                              void* d_out, int out_size, void* d_ws, size_t ws_size,
                              hipStream_t stream) {
    const float* x = (const float*)d_in[0];
    float* out = (float*)d_out;

    const unsigned n_pairs = (unsigned)(out_size / 2);      // 33,554,432
    const int block = 256;
    const unsigned chunk = block * 4;
    unsigned total_blocks = (n_pairs + chunk - 1) / chunk;
    unsigned grid = total_blocks < 2048u ? total_blocks : 2048u;

    patch_gather_kernel<<<grid, block, 0, stream>>>(x, out, n_pairs);
}

// Round 7
// 100.960 us; speedup vs baseline: 1.4546x; 1.0229x over previous
//
#include <hip/hip_runtime.h>

// out[c, y, w] = x[p, c, oy, ox]
//   iy = y / 126, jx = w / 126  (clamps never trigger for y,w < 1024)
//   oy = y - iy*126, ox = w - jx*126, p = iy*9 + jx
// x: (81, 64, 128, 128) f32; out: (64, 1024, 1024) f32. Pure injective gather,
// memory-bound, zero reuse.
//
// Round 7 = round 6 (nt loads+stores, 103.3 us) minus inner-loop guards.
// Work divides exactly (n_pairs = 2^25 = grid 2048 * block 256 * K 8 * 8 sweeps)
// so per-element bounds checks were pure overhead; batching 8 nt-loads ->
// wait -> 8 nt-stores removes per-step branches and doubles in-flight loads.
//
// Thread granule: one output PAIR (never splits a jx-segment since boundaries
// 126k are even; 8-B aligned both sides; lane-dense 512 B per instruction).

typedef float v2f __attribute__((ext_vector_type(2)));

__global__ __launch_bounds__(256) void patch_gather_kernel(
    const float* __restrict__ x, float* __restrict__ out,
    unsigned n_sweeps, unsigned tail_start, unsigned n_pairs) {
    const unsigned tid = threadIdx.x;
    const unsigned chunk = 256u * 8u;                       // pairs per block-sweep
    const unsigned stride = gridDim.x * chunk;              // pairs per grid-sweep
    unsigned base = blockIdx.x * chunk + tid;

    for (unsigned s = 0; s < n_sweeps; ++s, base += stride) {
        v2f pr[8];
        size_t oaddr[8];
        #pragma unroll
        for (int k = 0; k < 8; ++k) {
            const unsigned q = base + (unsigned)k * 256u;   // lanes contiguous per k
            const unsigned idx = q << 1;                    // flat output index (even)
            const unsigned c  = idx >> 20;                  // H*W = 2^20
            const unsigned y  = (idx >> 10) & 1023u;
            const unsigned w0 = idx & 1023u;                // even

            const unsigned iy = y / 126u;                   // magic-mul
            const unsigned oy = y - iy * 126u;
            const unsigned jx = w0 / 126u;                  // magic-mul
            const unsigned ox = w0 - jx * 126u;             // even

            const size_t addr = ((size_t)(iy * 576u + c) << 14)
                              + ((size_t)jx << 20) + (oy << 7) + ox;
            pr[k] = __builtin_nontemporal_load(
                reinterpret_cast<const v2f*>(&x[addr]));
            oaddr[k] = idx;
        }
        #pragma unroll
        for (int k = 0; k < 8; ++k) {
            __builtin_nontemporal_store(
                pr[k], reinterpret_cast<v2f*>(&out[oaddr[k]]));
        }
    }

    // Generic tail (empty for the real shape; kept for safety).
    for (unsigned q = tail_start + blockIdx.x * blockDim.x + tid; q < n_pairs;
         q += gridDim.x * blockDim.x) {
        const unsigned idx = q << 1;
        const unsigned c  = idx >> 20;
        const unsigned y  = (idx >> 10) & 1023u;
        const unsigned w0 = idx & 1023u;
        const unsigned iy = y / 126u;
        const unsigned oy = y - iy * 126u;
        const unsigned jx = w0 / 126u;
        const unsigned ox = w0 - jx * 126u;
        const size_t addr = ((size_t)(iy * 576u + c) << 14)
                          + ((size_t)jx << 20) + (oy << 7) + ox;
        const v2f v = __builtin_nontemporal_load(
            reinterpret_cast<const v2f*>(&x[addr]));
        __builtin_nontemporal_store(v, reinterpret_cast<v2f*>(&out[idx]));
    }
}

extern "C" void kernel_launch(void* const* d_in, const int* in_sizes, int n_in,
                              void* d_out, int out_size, void* d_ws, size_t ws_size,
                              hipStream_t stream) {
    const float* x = (const float*)d_in[0];
    float* out = (float*)d_out;

    const unsigned n_pairs = (unsigned)(out_size / 2);      // 2^25
    const unsigned grid = 2048, block = 256, K = 8;
    const unsigned per_sweep = grid * block * K;            // 2^22
    const unsigned n_sweeps = n_pairs / per_sweep;          // 8 (exact)
    const unsigned tail_start = n_sweeps * per_sweep;       // == n_pairs

    patch_gather_kernel<<<grid, block, 0, stream>>>(x, out, n_sweeps, tail_start, n_pairs);
}